// Round 1
// baseline (224.096 us; speedup 1.0000x reference)
//
#include <hip/hip_runtime.h>

// ---------------------------------------------------------------------------
// SelfAttention (dual cross-attention): B=4, S=1024, HID=1024, NH=16, DH=64
//   q1,k1,v1,q2,k2,v2 = x @ W*.T + b*   (bf16 MFMA, f32 accum)
//   out5 = attn(q1,k2,v2), out3 = attn(q2,k1,v1)
// ---------------------------------------------------------------------------

typedef __attribute__((ext_vector_type(8))) short bf16x8;
typedef __attribute__((ext_vector_type(4))) float f32x4;
typedef __attribute__((ext_vector_type(4))) short s16x4;

#define MFMA16(a, b, c) __builtin_amdgcn_mfma_f32_16x16x32_bf16(a, b, c, 0, 0, 0)

__device__ __forceinline__ unsigned short f2bf(float f) {
  unsigned u = __float_as_uint(f);
  u = (u + 0x7fffu + ((u >> 16) & 1u)) >> 16;  // RNE
  return (unsigned short)u;
}

__device__ __forceinline__ void gll16(const void* g, void* l) {
  __builtin_amdgcn_global_load_lds(
      (const __attribute__((address_space(1))) unsigned int*)g,
      (__attribute__((address_space(3))) unsigned int*)l, 16, 0, 0);
}

// ---------------------------------------------------------------------------
// Kernel 1: f32 -> bf16 conversion of x (4M) and the 6 weight matrices (6x1M)
// ---------------------------------------------------------------------------
__global__ __launch_bounds__(256) void convert_k(
    const float* __restrict__ x,
    const float* __restrict__ W0, const float* __restrict__ W1,
    const float* __restrict__ W2, const float* __restrict__ W3,
    const float* __restrict__ W4, const float* __restrict__ W5,
    short* __restrict__ xbf, short* __restrict__ wbf) {
  const int tid = blockIdx.x * 256 + threadIdx.x;
  const int e = tid << 2;
  const float* src;
  short* dst;
  int off;
  if (e < (4 << 20)) {
    src = x; dst = xbf; off = e;
  } else {
    const int j = e - (4 << 20);
    const int wsel = j >> 20;
    off = j & ((1 << 20) - 1);
    src = (wsel == 0) ? W0 : (wsel == 1) ? W1 : (wsel == 2) ? W2
        : (wsel == 3) ? W3 : (wsel == 4) ? W4 : W5;
    dst = wbf + ((size_t)wsel << 20);
  }
  const float4 v = *(const float4*)(src + off);
  s16x4 o;
  o.x = (short)f2bf(v.x);
  o.y = (short)f2bf(v.y);
  o.z = (short)f2bf(v.z);
  o.w = (short)f2bf(v.w);
  *(s16x4*)(dst + off) = o;
}

// ---------------------------------------------------------------------------
// Kernel 2: projection GEMM  C[p] = xbf @ W[p]^T + bias[p], written bf16 into
// attention layouts:
//   p%3==0 (Q): [b*16+h][s][d]            natural
//   p%3==1 (K): [b*16+h][s][d']           d' chunk-XOR-swizzled by (s&7)
//   p%3==2 (V): [b*16+h][s/64][d][s'']    64x64 tiles of V^T, s'' swizzled by (d&7)
// 128x128 tile, BK=64, 4 waves, global_load_lds width 16 (m97 structure).
// ---------------------------------------------------------------------------
__global__ __launch_bounds__(256) void proj_gemm(
    const short* __restrict__ A, const short* __restrict__ W,
    const float* __restrict__ bq, const float* __restrict__ bk,
    const float* __restrict__ bv, const float* __restrict__ bq2,
    const float* __restrict__ bk2, const float* __restrict__ bv2,
    short* __restrict__ qkv) {
  __shared__ __align__(16) short As[128 * 64];
  __shared__ __align__(16) short Bs[128 * 64];
  const int p = blockIdx.z;
  const int m0 = blockIdx.x << 7, n0 = blockIdx.y << 7;
  const short* B = W + ((size_t)p << 20);
  const int t = threadIdx.x, lane = t & 63, w = t >> 6;
  const int g = lane >> 4, lr = lane & 15;
  const int srow = (w << 5) + (lane >> 3);  // + i*8 -> rows 0..127
  const int scol = (lane & 7) << 3;
  const int wm = ((w >> 1) << 6), wn = ((w & 1) << 6);
  f32x4 acc[4][4] = {};

  for (int k0 = 0; k0 < 1024; k0 += 64) {
#pragma unroll
    for (int i = 0; i < 4; ++i) {
      gll16(A + (size_t)(m0 + srow + i * 8) * 1024 + k0 + scol,
            &As[(w << 11) + (i << 9)]);
      gll16(B + (size_t)(n0 + srow + i * 8) * 1024 + k0 + scol,
            &Bs[(w << 11) + (i << 9)]);
    }
    __syncthreads();
#pragma unroll
    for (int kk = 0; kk < 2; ++kk) {
      bf16x8 af[4], bfm[4];
#pragma unroll
      for (int mi = 0; mi < 4; ++mi)
        af[mi] = *(const bf16x8*)&As[(wm + mi * 16 + lr) * 64 + kk * 32 + g * 8];
#pragma unroll
      for (int nj = 0; nj < 4; ++nj)
        bfm[nj] = *(const bf16x8*)&Bs[(wn + nj * 16 + lr) * 64 + kk * 32 + g * 8];
#pragma unroll
      for (int mi = 0; mi < 4; ++mi)
#pragma unroll
        for (int nj = 0; nj < 4; ++nj)
          acc[mi][nj] = MFMA16(af[mi], bfm[nj], acc[mi][nj]);
    }
    __syncthreads();
  }

  const float* bias = (p == 0) ? bq : (p == 1) ? bk : (p == 2) ? bv
                    : (p == 3) ? bq2 : (p == 4) ? bk2 : bv2;
  const int ptype = (p == 0 || p == 3) ? 0 : (p == 1 || p == 4) ? 1 : 2;
  unsigned short* dst = (unsigned short*)qkv + ((size_t)p << 22);
#pragma unroll
  for (int nj = 0; nj < 4; ++nj) {
    const int n = n0 + wn + nj * 16 + lr;
    const float bb = bias[n];
    const int h = n >> 6, d = n & 63;
#pragma unroll
    for (int mi = 0; mi < 4; ++mi) {
#pragma unroll
      for (int r = 0; r < 4; ++r) {
        const int m = m0 + wm + mi * 16 + (g << 2) + r;
        const int b = m >> 10, s = m & 1023;
        const unsigned short val = f2bf(acc[mi][nj][r] + bb);
        size_t idx;
        if (ptype == 0) {
          idx = ((size_t)(((b << 4) + h) * 1024 + s) << 6) + d;
        } else if (ptype == 1) {
          const int d2 = (d & 7) | (((d >> 3) ^ (s & 7)) << 3);
          idx = ((size_t)(((b << 4) + h) * 1024 + s) << 6) + d2;
        } else {
          const int tt = s >> 6, s2 = s & 63;
          const int s3 = (s2 & 7) | (((s2 >> 3) ^ (d & 7)) << 3);
          idx = ((size_t)((((b << 4) + h) * 16 + tt) * 64 + d) << 6) + s3;
        }
        dst[idx] = val;
      }
    }
  }
}

// ---------------------------------------------------------------------------
// Kernel 3: flash attention. Block = 4 waves, Q-tile 64 rows (16/wave),
// KV tile 64 staged in LDS (pre-swizzled in global so linear global_load_lds
// + XOR'd ds_read_b128 is conflict-free). Online softmax per lane (4 q-rows),
// P roundtrip through per-wave LDS region. XCD-aware 1D block swizzle.
// ---------------------------------------------------------------------------
__global__ __launch_bounds__(256) void attn_k(const short* __restrict__ qkv,
                                              float* __restrict__ out) {
  __shared__ __align__(16) short Ks[64 * 64];
  __shared__ __align__(16) short Vs[64 * 64];
  __shared__ __align__(16) short Ps[4 * 16 * 64];

  const int L = blockIdx.x;  // 2048 blocks
  const int xcd = L & 7, ss = L >> 3;
  const int qt = ss & 15, pg = ss >> 4;
  const int pp = xcd + (pg << 3);  // 0..127; all 16 q-tiles of a head share an XCD
  const int hb = pp & 63, dir = pp >> 6;

  const short* Q = qkv + ((size_t)(dir ? 3 : 0) << 22) + ((size_t)hb << 16);
  const short* K = qkv + ((size_t)(dir ? 1 : 4) << 22) + ((size_t)hb << 16);
  const short* V = qkv + ((size_t)(dir ? 2 : 5) << 22) + ((size_t)hb << 16);
  float* O = out + ((size_t)dir << 22);

  const int t = threadIdx.x, lane = t & 63, w = t >> 6;
  const int g = lane >> 4, lr = lane & 15;

  const int qrow = (qt << 6) + (w << 4) + lr;
  bf16x8 qf[2];
  qf[0] = *(const bf16x8*)(Q + qrow * 64 + g * 8);
  qf[1] = *(const bf16x8*)(Q + qrow * 64 + 32 + g * 8);

  f32x4 oacc[4] = {};
  float mrow[4], lrow[4];
#pragma unroll
  for (int r = 0; r < 4; ++r) { mrow[r] = -3.0e38f; lrow[r] = 0.0f; }
  const float CSC = 0.18033688f;  // (1/8) * log2(e)

  const int srow = (w << 4) + (lane >> 3);  // staging row 0..63
  const int scol = (lane & 7) << 3;

  for (int kt = 0; kt < 16; ++kt) {
#pragma unroll
    for (int i = 0; i < 2; ++i) {
      gll16(K + (size_t)((kt << 6) + srow + i * 8) * 64 + scol,
            &Ks[(w << 10) + (i << 9)]);
      gll16(V + (size_t)(kt << 12) + (size_t)(srow + i * 8) * 64 + scol,
            &Vs[(w << 10) + (i << 9)]);
    }
    __syncthreads();

    // ---- S = Q K^T (raw, scale applied in softmax) ----
    f32x4 sacc[4] = {};
#pragma unroll
    for (int dk = 0; dk < 2; ++dk) {
#pragma unroll
      for (int kn = 0; kn < 4; ++kn) {
        const int krow = kn * 16 + lr;
        const bf16x8 kf = *(const bf16x8*)
            &Ks[krow * 64 + ((((dk << 6) + (g << 4)) ^ ((krow & 7) << 4)) >> 1)];
        sacc[kn] = MFMA16(qf[dk], kf, sacc[kn]);
      }
    }

    // ---- online softmax; lane owns q-rows g*4+r, k-cols kn*16+lr ----
#pragma unroll
    for (int r = 0; r < 4; ++r) {
      float tm = fmaxf(fmaxf(sacc[0][r], sacc[1][r]),
                       fmaxf(sacc[2][r], sacc[3][r]));
      tm = fmaxf(tm, __shfl_xor(tm, 1));
      tm = fmaxf(tm, __shfl_xor(tm, 2));
      tm = fmaxf(tm, __shfl_xor(tm, 4));
      tm = fmaxf(tm, __shfl_xor(tm, 8));
      const float mnew = fmaxf(mrow[r], tm * CSC);
      const float scale = exp2f(mrow[r] - mnew);
      mrow[r] = mnew;
      const float p0 = exp2f(sacc[0][r] * CSC - mnew);
      const float p1 = exp2f(sacc[1][r] * CSC - mnew);
      const float p2 = exp2f(sacc[2][r] * CSC - mnew);
      const float p3 = exp2f(sacc[3][r] * CSC - mnew);
      float sum = (p0 + p1) + (p2 + p3);
      sum += __shfl_xor(sum, 1);
      sum += __shfl_xor(sum, 2);
      sum += __shfl_xor(sum, 4);
      sum += __shfl_xor(sum, 8);
      lrow[r] = lrow[r] * scale + sum;
#pragma unroll
      for (int dn = 0; dn < 4; ++dn) oacc[dn][r] *= scale;
      // P write (bf16, swizzled) into per-wave region
      const int prow = (g << 2) + r;
      const int pbase = (w << 10) + prow * 64;
      const int sw = (prow & 7) << 4;
      unsigned short* Pu = (unsigned short*)Ps;
      Pu[pbase + ((((0 << 5) + (lr << 1)) ^ sw) >> 1)] = f2bf(p0);
      Pu[pbase + ((((1 << 5) + (lr << 1)) ^ sw) >> 1)] = f2bf(p1);
      Pu[pbase + ((((2 << 5) + (lr << 1)) ^ sw) >> 1)] = f2bf(p2);
      Pu[pbase + ((((3 << 5) + (lr << 1)) ^ sw) >> 1)] = f2bf(p3);
    }

    // ---- O += P V ----
#pragma unroll
    for (int kk = 0; kk < 2; ++kk) {
      const bf16x8 pf = *(const bf16x8*)
          &Ps[(w << 10) + lr * 64 + ((((kk << 6) + (g << 4)) ^ ((lr & 7) << 4)) >> 1)];
#pragma unroll
      for (int dn = 0; dn < 4; ++dn) {
        const int vrow = dn * 16 + lr;
        const bf16x8 vf = *(const bf16x8*)
            &Vs[vrow * 64 + ((((kk << 6) + (g << 4)) ^ ((vrow & 7) << 4)) >> 1)];
        oacc[dn] = MFMA16(pf, vf, oacc[dn]);
      }
    }
    __syncthreads();
  }

  // ---- epilogue: out[b][q][h*64+d] = oacc / l ----
  const int b = hb >> 4, h = hb & 15;
#pragma unroll
  for (int dn = 0; dn < 4; ++dn) {
#pragma unroll
    for (int r = 0; r < 4; ++r) {
      const int q = (qt << 6) + (w << 4) + (g << 2) + r;
      const int d = dn * 16 + lr;
      O[((size_t)(b * 1024 + q) << 10) + h * 64 + d] = oacc[dn][r] / lrow[r];
    }
  }
}

// ---------------------------------------------------------------------------
extern "C" void kernel_launch(void* const* d_in, const int* in_sizes, int n_in,
                              void* d_out, int out_size, void* d_ws,
                              size_t ws_size, hipStream_t stream) {
  const float* x   = (const float*)d_in[0];
  const float* Wq  = (const float*)d_in[1];
  const float* bq  = (const float*)d_in[2];
  const float* Wk  = (const float*)d_in[3];
  const float* bk  = (const float*)d_in[4];
  const float* Wv  = (const float*)d_in[5];
  const float* bv  = (const float*)d_in[6];
  const float* Wq2 = (const float*)d_in[7];
  const float* bq2 = (const float*)d_in[8];
  const float* Wk2 = (const float*)d_in[9];
  const float* bk2 = (const float*)d_in[10];
  const float* Wv2 = (const float*)d_in[11];
  const float* bv2 = (const float*)d_in[12];

  char* ws = (char*)d_ws;
  short* xbf = (short*)ws;                      // 8 MB
  short* wbf = (short*)(ws + 8388608);          // 12 MB
  short* qkv = (short*)(ws + 20971520);         // 6 x 8 MB

  convert_k<<<10240, 256, 0, stream>>>(x, Wq, Wk, Wv, Wq2, Wk2, Wv2, xbf, wbf);
  proj_gemm<<<dim3(32, 8, 6), 256, 0, stream>>>(xbf, wbf, bq, bk, bv, bq2, bk2,
                                                bv2, qkv);
  attn_k<<<2048, 256, 0, stream>>>(qkv, (float*)d_out);
}

// Round 2
// 187.847 us; speedup vs baseline: 1.1930x; 1.1930x over previous
//
#include <hip/hip_runtime.h>

// ---------------------------------------------------------------------------
// SelfAttention (dual cross-attention): B=4, S=1024, HID=1024, NH=16, DH=64
//   q1,k1,v1,q2,k2,v2 = x @ W*.T + b*   (bf16 MFMA, f32 accum)
//   out5 = attn(q1,k2,v2), out3 = attn(q2,k1,v1)
// ---------------------------------------------------------------------------

typedef __attribute__((ext_vector_type(8))) short bf16x8;
typedef __attribute__((ext_vector_type(4))) float f32x4;
typedef __attribute__((ext_vector_type(4))) short s16x4;

#define MFMA16(a, b, c) __builtin_amdgcn_mfma_f32_16x16x32_bf16(a, b, c, 0, 0, 0)

__device__ __forceinline__ unsigned short f2bf(float f) {
  unsigned u = __float_as_uint(f);
  u = (u + 0x7fffu + ((u >> 16) & 1u)) >> 16;  // RNE
  return (unsigned short)u;
}

__device__ __forceinline__ void gll16(const void* g, void* l) {
  __builtin_amdgcn_global_load_lds(
      (const __attribute__((address_space(1))) unsigned int*)g,
      (__attribute__((address_space(3))) unsigned int*)l, 16, 0, 0);
}

// ---------------------------------------------------------------------------
// Kernel 1: f32 -> bf16 conversion of x (4M) and the 6 weight matrices (6x1M)
// ---------------------------------------------------------------------------
__global__ __launch_bounds__(256) void convert_k(
    const float* __restrict__ x,
    const float* __restrict__ W0, const float* __restrict__ W1,
    const float* __restrict__ W2, const float* __restrict__ W3,
    const float* __restrict__ W4, const float* __restrict__ W5,
    short* __restrict__ xbf, short* __restrict__ wbf) {
  const int tid = blockIdx.x * 256 + threadIdx.x;
  const int e = tid << 2;
  const float* src;
  short* dst;
  int off;
  if (e < (4 << 20)) {
    src = x; dst = xbf; off = e;
  } else {
    const int j = e - (4 << 20);
    const int wsel = j >> 20;
    off = j & ((1 << 20) - 1);
    src = (wsel == 0) ? W0 : (wsel == 1) ? W1 : (wsel == 2) ? W2
        : (wsel == 3) ? W3 : (wsel == 4) ? W4 : W5;
    dst = wbf + ((size_t)wsel << 20);
  }
  const float4 v = *(const float4*)(src + off);
  s16x4 o;
  o.x = (short)f2bf(v.x);
  o.y = (short)f2bf(v.y);
  o.z = (short)f2bf(v.z);
  o.w = (short)f2bf(v.w);
  *(s16x4*)(dst + off) = o;
}

// ---------------------------------------------------------------------------
// Kernel 2: projection GEMM  C[p] = xbf @ W[p]^T + bias[p], written bf16 into
// attention layouts:
//   p%3==0 (Q): [b*16+h][s][d]            natural
//   p%3==1 (K): [b*16+h][s][d']           d' chunk-XOR-swizzled by (s&7)
//   p%3==2 (V): [b*16+h][s/64][d][s'']    64x64 tiles of V^T, s'' swizzled by (d&7)
// 128x128 tile, BK=64, 4 waves, global_load_lds width 16 (m97 structure).
// ---------------------------------------------------------------------------
__global__ __launch_bounds__(256) void proj_gemm(
    const short* __restrict__ A, const short* __restrict__ W,
    const float* __restrict__ bq, const float* __restrict__ bk,
    const float* __restrict__ bv, const float* __restrict__ bq2,
    const float* __restrict__ bk2, const float* __restrict__ bv2,
    short* __restrict__ qkv) {
  __shared__ __align__(16) short As[128 * 64];
  __shared__ __align__(16) short Bs[128 * 64];
  const int p = blockIdx.z;
  const int m0 = blockIdx.x << 7, n0 = blockIdx.y << 7;
  const short* B = W + ((size_t)p << 20);
  const int t = threadIdx.x, lane = t & 63, w = t >> 6;
  const int g = lane >> 4, lr = lane & 15;
  const int srow = (w << 5) + (lane >> 3);  // + i*8 -> rows 0..127
  const int scol = (lane & 7) << 3;
  const int wm = ((w >> 1) << 6), wn = ((w & 1) << 6);
  f32x4 acc[4][4] = {};

  for (int k0 = 0; k0 < 1024; k0 += 64) {
#pragma unroll
    for (int i = 0; i < 4; ++i) {
      gll16(A + (size_t)(m0 + srow + i * 8) * 1024 + k0 + scol,
            &As[(w << 11) + (i << 9)]);
      gll16(B + (size_t)(n0 + srow + i * 8) * 1024 + k0 + scol,
            &Bs[(w << 11) + (i << 9)]);
    }
    __syncthreads();
#pragma unroll
    for (int kk = 0; kk < 2; ++kk) {
      bf16x8 af[4], bfm[4];
#pragma unroll
      for (int mi = 0; mi < 4; ++mi)
        af[mi] = *(const bf16x8*)&As[(wm + mi * 16 + lr) * 64 + kk * 32 + g * 8];
#pragma unroll
      for (int nj = 0; nj < 4; ++nj)
        bfm[nj] = *(const bf16x8*)&Bs[(wn + nj * 16 + lr) * 64 + kk * 32 + g * 8];
#pragma unroll
      for (int mi = 0; mi < 4; ++mi)
#pragma unroll
        for (int nj = 0; nj < 4; ++nj)
          acc[mi][nj] = MFMA16(af[mi], bfm[nj], acc[mi][nj]);
    }
    __syncthreads();
  }

  const float* bias = (p == 0) ? bq : (p == 1) ? bk : (p == 2) ? bv
                    : (p == 3) ? bq2 : (p == 4) ? bk2 : bv2;
  const int ptype = (p == 0 || p == 3) ? 0 : (p == 1 || p == 4) ? 1 : 2;
  unsigned short* dst = (unsigned short*)qkv + ((size_t)p << 22);
#pragma unroll
  for (int nj = 0; nj < 4; ++nj) {
    const int n = n0 + wn + nj * 16 + lr;
    const float bb = bias[n];
    const int h = n >> 6, d = n & 63;
#pragma unroll
    for (int mi = 0; mi < 4; ++mi) {
#pragma unroll
      for (int r = 0; r < 4; ++r) {
        const int m = m0 + wm + mi * 16 + (g << 2) + r;
        const int b = m >> 10, s = m & 1023;
        const unsigned short val = f2bf(acc[mi][nj][r] + bb);
        size_t idx;
        if (ptype == 0) {
          idx = ((size_t)(((b << 4) + h) * 1024 + s) << 6) + d;
        } else if (ptype == 1) {
          const int d2 = (d & 7) | (((d >> 3) ^ (s & 7)) << 3);
          idx = ((size_t)(((b << 4) + h) * 1024 + s) << 6) + d2;
        } else {
          const int tt = s >> 6, s2 = s & 63;
          const int s3 = (s2 & 7) | (((s2 >> 3) ^ (d & 7)) << 3);
          idx = ((size_t)((((b << 4) + h) * 16 + tt) * 64 + d) << 6) + s3;
        }
        dst[idx] = val;
      }
    }
  }
}

// ---------------------------------------------------------------------------
// Kernel 3: flash attention. Block = 4 waves, Q-tile 64 rows (16/wave),
// KV tile 64 double-buffered in LDS (2-phase pipeline: stage next tile's
// global_load_lds before compute, counted drain at tile end). Online softmax
// with defer-max (T13, THR=8 log2 units) and MFMA-ones row-sum (no sum
// shuffle reduce). P roundtrip through per-wave LDS region (XOR-swizzled).
// XCD-aware 1D block swizzle.
// ---------------------------------------------------------------------------
__global__ __launch_bounds__(256) void attn_k(const short* __restrict__ qkv,
                                              float* __restrict__ out) {
  __shared__ __align__(16) short Ks[2][64 * 64];
  __shared__ __align__(16) short Vs[2][64 * 64];
  __shared__ __align__(16) short Ps[4 * 16 * 64];

  const int L = blockIdx.x;  // 2048 blocks
  const int xcd = L & 7, ss = L >> 3;
  const int qt = ss & 15, pg = ss >> 4;
  const int pp = xcd + (pg << 3);  // 0..127; all 16 q-tiles of a head share an XCD
  const int hb = pp & 63, dir = pp >> 6;

  const short* Q = qkv + ((size_t)(dir ? 3 : 0) << 22) + ((size_t)hb << 16);
  const short* K = qkv + ((size_t)(dir ? 1 : 4) << 22) + ((size_t)hb << 16);
  const short* V = qkv + ((size_t)(dir ? 2 : 5) << 22) + ((size_t)hb << 16);
  float* O = out + ((size_t)dir << 22);

  const int t = threadIdx.x, lane = t & 63, w = t >> 6;
  const int g = lane >> 4, lr = lane & 15;

  const int qrow = (qt << 6) + (w << 4) + lr;
  bf16x8 qf[2];
  qf[0] = *(const bf16x8*)(Q + qrow * 64 + g * 8);
  qf[1] = *(const bf16x8*)(Q + qrow * 64 + 32 + g * 8);

  const bf16x8 onesf = {0x3F80, 0x3F80, 0x3F80, 0x3F80,
                        0x3F80, 0x3F80, 0x3F80, 0x3F80};

  f32x4 oacc[4] = {};
  f32x4 lacc = {};
  float mrow[4];
#pragma unroll
  for (int r = 0; r < 4; ++r) mrow[r] = -3.0e38f;
  const float CSC = 0.18033688f;  // (1/8) * log2(e)

  const int srow = (w << 4) + (lane >> 3);  // staging row 0..63
  const int scol = (lane & 7) << 3;

  auto stage = [&](int kt, int buf) {
#pragma unroll
    for (int i = 0; i < 2; ++i) {
      gll16(K + (size_t)((kt << 6) + srow + i * 8) * 64 + scol,
            &Ks[buf][(w << 10) + (i << 9)]);
      gll16(V + (size_t)(kt << 12) + (size_t)(srow + i * 8) * 64 + scol,
            &Vs[buf][(w << 10) + (i << 9)]);
    }
  };

  stage(0, 0);
  asm volatile("s_waitcnt vmcnt(0)" ::: "memory");
  __builtin_amdgcn_s_barrier();

  int cur = 0;
  for (int kt = 0; kt < 16; ++kt) {
    if (kt < 15) stage(kt + 1, cur ^ 1);  // loads in flight during compute

    // ---- S = Q K^T (raw, scale folded into softmax) ----
    f32x4 sacc[4] = {};
#pragma unroll
    for (int dk = 0; dk < 2; ++dk) {
#pragma unroll
      for (int kn = 0; kn < 4; ++kn) {
        const int krow = kn * 16 + lr;
        const bf16x8 kf = *(const bf16x8*)
            &Ks[cur][krow * 64 +
                     ((((dk << 6) + (g << 4)) ^ ((krow & 7) << 4)) >> 1)];
        sacc[kn] = MFMA16(qf[dk], kf, sacc[kn]);
      }
    }

    // ---- online softmax with defer-max; lane: rows g*4+r, cols kn*16+lr ----
#pragma unroll
    for (int r = 0; r < 4; ++r) {
      float tm = fmaxf(fmaxf(sacc[0][r], sacc[1][r]),
                       fmaxf(sacc[2][r], sacc[3][r]));
      // defer-max: only rescale when some row's tile max exceeds m + 8 (log2)
      const bool ok = __all(fmaf(tm, CSC, -mrow[r]) <= 8.0f);
      if (!ok) {
        tm = fmaxf(tm, __shfl_xor(tm, 1));
        tm = fmaxf(tm, __shfl_xor(tm, 2));
        tm = fmaxf(tm, __shfl_xor(tm, 4));
        tm = fmaxf(tm, __shfl_xor(tm, 8));
        const float mnew = fmaxf(mrow[r], tm * CSC);
        const float scale = exp2f(mrow[r] - mnew);
        mrow[r] = mnew;
        lacc[r] *= scale;
#pragma unroll
        for (int dn = 0; dn < 4; ++dn) oacc[dn][r] *= scale;
      }
      const float p0 = exp2f(fmaf(sacc[0][r], CSC, -mrow[r]));
      const float p1 = exp2f(fmaf(sacc[1][r], CSC, -mrow[r]));
      const float p2 = exp2f(fmaf(sacc[2][r], CSC, -mrow[r]));
      const float p3 = exp2f(fmaf(sacc[3][r], CSC, -mrow[r]));
      // P write (bf16, swizzled) into per-wave region
      const int prow = (g << 2) + r;
      const int pbase = (w << 10) + prow * 64;
      const int sw = (prow & 7) << 4;
      unsigned short* Pu = (unsigned short*)Ps;
      Pu[pbase + ((((0 << 5) + (lr << 1)) ^ sw) >> 1)] = f2bf(p0);
      Pu[pbase + ((((1 << 5) + (lr << 1)) ^ sw) >> 1)] = f2bf(p1);
      Pu[pbase + ((((2 << 5) + (lr << 1)) ^ sw) >> 1)] = f2bf(p2);
      Pu[pbase + ((((3 << 5) + (lr << 1)) ^ sw) >> 1)] = f2bf(p3);
    }

    // ---- O += P V ; l += P @ ones (row-sum via MFMA) ----
#pragma unroll
    for (int kk = 0; kk < 2; ++kk) {
      const bf16x8 pf = *(const bf16x8*)
          &Ps[(w << 10) + lr * 64 +
              ((((kk << 6) + (g << 4)) ^ ((lr & 7) << 4)) >> 1)];
      lacc = MFMA16(pf, onesf, lacc);
#pragma unroll
      for (int dn = 0; dn < 4; ++dn) {
        const int vrow = dn * 16 + lr;
        const bf16x8 vf = *(const bf16x8*)
            &Vs[cur][vrow * 64 +
                     ((((kk << 6) + (g << 4)) ^ ((vrow & 7) << 4)) >> 1)];
        oacc[dn] = MFMA16(pf, vf, oacc[dn]);
      }
    }

    asm volatile("s_waitcnt vmcnt(0)" ::: "memory");
    __builtin_amdgcn_s_barrier();
    cur ^= 1;
  }

  // ---- epilogue: out[b][q][h*64+d] = oacc / l ----
  const int b = hb >> 4, h = hb & 15;
  float rl[4];
#pragma unroll
  for (int r = 0; r < 4; ++r) rl[r] = 1.0f / lacc[r];
#pragma unroll
  for (int dn = 0; dn < 4; ++dn) {
#pragma unroll
    for (int r = 0; r < 4; ++r) {
      const int q = (qt << 6) + (w << 4) + (g << 2) + r;
      const int d = dn * 16 + lr;
      O[((size_t)(b * 1024 + q) << 10) + h * 64 + d] = oacc[dn][r] * rl[r];
    }
  }
}

// ---------------------------------------------------------------------------
extern "C" void kernel_launch(void* const* d_in, const int* in_sizes, int n_in,
                              void* d_out, int out_size, void* d_ws,
                              size_t ws_size, hipStream_t stream) {
  const float* x   = (const float*)d_in[0];
  const float* Wq  = (const float*)d_in[1];
  const float* bq  = (const float*)d_in[2];
  const float* Wk  = (const float*)d_in[3];
  const float* bk  = (const float*)d_in[4];
  const float* Wv  = (const float*)d_in[5];
  const float* bv  = (const float*)d_in[6];
  const float* Wq2 = (const float*)d_in[7];
  const float* bq2 = (const float*)d_in[8];
  const float* Wk2 = (const float*)d_in[9];
  const float* bk2 = (const float*)d_in[10];
  const float* Wv2 = (const float*)d_in[11];
  const float* bv2 = (const float*)d_in[12];

  char* ws = (char*)d_ws;
  short* xbf = (short*)ws;                      // 8 MB
  short* wbf = (short*)(ws + 8388608);          // 12 MB
  short* qkv = (short*)(ws + 20971520);         // 6 x 8 MB

  convert_k<<<10240, 256, 0, stream>>>(x, Wq, Wk, Wv, Wq2, Wk2, Wv2, xbf, wbf);
  proj_gemm<<<dim3(32, 8, 6), 256, 0, stream>>>(xbf, wbf, bq, bk, bv, bq2, bk2,
                                                bv2, qkv);
  attn_k<<<2048, 256, 0, stream>>>(qkv, (float*)d_out);
}

// Round 3
// 174.491 us; speedup vs baseline: 1.2843x; 1.0765x over previous
//
#include <hip/hip_runtime.h>

// ---------------------------------------------------------------------------
// SelfAttention (dual cross-attention): B=4, S=1024, HID=1024, NH=16, DH=64
//   q1,k1,v1,q2,k2,v2 = x @ W*.T + b*   (bf16 MFMA, f32 accum)
//   out5 = attn(q1,k2,v2), out3 = attn(q2,k1,v1)
// ---------------------------------------------------------------------------

typedef __attribute__((ext_vector_type(8))) short bf16x8;
typedef __attribute__((ext_vector_type(4))) short bf16x4;
typedef __attribute__((ext_vector_type(4))) float f32x4;
typedef __attribute__((ext_vector_type(4))) short s16x4;

#define MFMA16(a, b, c) __builtin_amdgcn_mfma_f32_16x16x32_bf16(a, b, c, 0, 0, 0)

// K=16 bf16 MFMA (A/B = 4 bf16 in 2 VGPR). Builtin name differs across ROCm;
// chain _1k (gfx90a-lineage, kept on gfx950) -> new-style -> inline asm.
__device__ __forceinline__ f32x4 mfma16k(bf16x4 a, bf16x4 b, f32x4 c) {
#if __has_builtin(__builtin_amdgcn_mfma_f32_16x16x16bf16_1k)
  return __builtin_amdgcn_mfma_f32_16x16x16bf16_1k(a, b, c, 0, 0, 0);
#elif __has_builtin(__builtin_amdgcn_mfma_f32_16x16x16_bf16)
  return __builtin_amdgcn_mfma_f32_16x16x16_bf16(a, b, c, 0, 0, 0);
#else
  asm volatile("v_mfma_f32_16x16x16_bf16 %0, %1, %2, %0"
               : "+v"(c) : "v"(a), "v"(b));
  return c;
#endif
}

__device__ __forceinline__ unsigned short f2bf(float f) {
  unsigned u = __float_as_uint(f);
  u = (u + 0x7fffu + ((u >> 16) & 1u)) >> 16;  // RNE
  return (unsigned short)u;
}

__device__ __forceinline__ unsigned cvt_pk_bf16(float lo, float hi) {
  unsigned r;
  asm("v_cvt_pk_bf16_f32 %0, %1, %2" : "=v"(r) : "v"(lo), "v"(hi));
  return r;
}

__device__ __forceinline__ void gll16(const void* g, void* l) {
  __builtin_amdgcn_global_load_lds(
      (const __attribute__((address_space(1))) unsigned int*)g,
      (__attribute__((address_space(3))) unsigned int*)l, 16, 0, 0);
}

// ---------------------------------------------------------------------------
// Kernel 1: f32 -> bf16 conversion of x (4M) and the 6 weight matrices (6x1M)
// ---------------------------------------------------------------------------
__global__ __launch_bounds__(256) void convert_k(
    const float* __restrict__ x,
    const float* __restrict__ W0, const float* __restrict__ W1,
    const float* __restrict__ W2, const float* __restrict__ W3,
    const float* __restrict__ W4, const float* __restrict__ W5,
    short* __restrict__ xbf, short* __restrict__ wbf) {
  const int tid = blockIdx.x * 256 + threadIdx.x;
  const int e = tid << 2;
  const float* src;
  short* dst;
  int off;
  if (e < (4 << 20)) {
    src = x; dst = xbf; off = e;
  } else {
    const int j = e - (4 << 20);
    const int wsel = j >> 20;
    off = j & ((1 << 20) - 1);
    src = (wsel == 0) ? W0 : (wsel == 1) ? W1 : (wsel == 2) ? W2
        : (wsel == 3) ? W3 : (wsel == 4) ? W4 : W5;
    dst = wbf + ((size_t)wsel << 20);
  }
  const float4 v = *(const float4*)(src + off);
  s16x4 o;
  o.x = (short)f2bf(v.x);
  o.y = (short)f2bf(v.y);
  o.z = (short)f2bf(v.z);
  o.w = (short)f2bf(v.w);
  *(s16x4*)(dst + off) = o;
}

// ---------------------------------------------------------------------------
// Kernel 2: projection GEMM  C[p] = xbf @ W[p]^T + bias[p], bf16 out in
// attention layouts (Q natural, K d-chunk-swizzled, V transposed 64x64 tiles
// s-chunk-swizzled). 128x128 tile, BK=64, 4 waves, 2-phase double-buffered
// global_load_lds pipeline, XCD/panel-aware block mapping:
//   each XCD owns 6 (n,p) B-panels; m-major order reuses each A-panel 6x.
// ---------------------------------------------------------------------------
__global__ __launch_bounds__(256) void proj_gemm(
    const short* __restrict__ A, const short* __restrict__ W,
    const float* __restrict__ bq, const float* __restrict__ bk,
    const float* __restrict__ bv, const float* __restrict__ bq2,
    const float* __restrict__ bk2, const float* __restrict__ bv2,
    short* __restrict__ qkv) {
  __shared__ __align__(16) short As[2][128 * 64];
  __shared__ __align__(16) short Bs[2][128 * 64];
  const int wg = blockIdx.x;            // 1536
  const int xcd = wg & 7, i = wg >> 3;  // 192 blocks per XCD
  const int mb = i / 6, j = i - mb * 6;
  const int panel = xcd * 6 + j;        // 0..47
  const int p = panel >> 3, n_ = panel & 7;
  const int m0 = mb << 7, n0 = n_ << 7;

  const short* B = W + ((size_t)p << 20);
  const int t = threadIdx.x, lane = t & 63, w = t >> 6;
  const int g = lane >> 4, lr = lane & 15;
  const int srow = (w << 5) + (lane >> 3);  // + i*8 -> rows 0..127
  const int scol = (lane & 7) << 3;
  const int wm = ((w >> 1) << 6), wn = ((w & 1) << 6);
  f32x4 acc[4][4] = {};

  auto stage = [&](int k0, int buf) {
#pragma unroll
    for (int ii = 0; ii < 4; ++ii) {
      gll16(A + (size_t)(m0 + srow + ii * 8) * 1024 + k0 + scol,
            &As[buf][(w << 11) + (ii << 9)]);
      gll16(B + (size_t)(n0 + srow + ii * 8) * 1024 + k0 + scol,
            &Bs[buf][(w << 11) + (ii << 9)]);
    }
  };

  stage(0, 0);
  asm volatile("s_waitcnt vmcnt(0)" ::: "memory");
  __builtin_amdgcn_s_barrier();

  int cur = 0;
  for (int kt = 0; kt < 16; ++kt) {
    if (kt < 15) stage((kt + 1) << 6, cur ^ 1);  // loads fly during compute
#pragma unroll
    for (int kk = 0; kk < 2; ++kk) {
      bf16x8 af[4], bfm[4];
#pragma unroll
      for (int mi = 0; mi < 4; ++mi)
        af[mi] = *(const bf16x8*)
            &As[cur][(wm + mi * 16 + lr) * 64 + kk * 32 + g * 8];
#pragma unroll
      for (int nj = 0; nj < 4; ++nj)
        bfm[nj] = *(const bf16x8*)
            &Bs[cur][(wn + nj * 16 + lr) * 64 + kk * 32 + g * 8];
      __builtin_amdgcn_s_setprio(1);
#pragma unroll
      for (int mi = 0; mi < 4; ++mi)
#pragma unroll
        for (int nj = 0; nj < 4; ++nj)
          acc[mi][nj] = MFMA16(af[mi], bfm[nj], acc[mi][nj]);
      __builtin_amdgcn_s_setprio(0);
    }
    asm volatile("s_waitcnt vmcnt(0)" ::: "memory");
    __builtin_amdgcn_s_barrier();
    cur ^= 1;
  }

  const float* bias = (p == 0) ? bq : (p == 1) ? bk : (p == 2) ? bv
                    : (p == 3) ? bq2 : (p == 4) ? bk2 : bv2;
  const int ptype = (p == 0 || p == 3) ? 0 : (p == 1 || p == 4) ? 1 : 2;
  unsigned short* dst = (unsigned short*)qkv + ((size_t)p << 22);
#pragma unroll
  for (int nj = 0; nj < 4; ++nj) {
    const int n = n0 + wn + nj * 16 + lr;
    const float bb = bias[n];
    const int h = n >> 6, d = n & 63;
#pragma unroll
    for (int mi = 0; mi < 4; ++mi) {
#pragma unroll
      for (int r = 0; r < 4; ++r) {
        const int m = m0 + wm + mi * 16 + (g << 2) + r;
        const int b = m >> 10, s = m & 1023;
        const unsigned short val = f2bf(acc[mi][nj][r] + bb);
        size_t idx;
        if (ptype == 0) {
          idx = ((size_t)(((b << 4) + h) * 1024 + s) << 6) + d;
        } else if (ptype == 1) {
          const int d2 = (d & 7) | (((d >> 3) ^ (s & 7)) << 3);
          idx = ((size_t)(((b << 4) + h) * 1024 + s) << 6) + d2;
        } else {
          const int tt = s >> 6, s2 = s & 63;
          const int s3 = (s2 & 7) | (((s2 >> 3) ^ (d & 7)) << 3);
          idx = ((size_t)((((b << 4) + h) * 16 + tt) * 64 + d) << 6) + s3;
        }
        dst[idx] = val;
      }
    }
  }
}

// ---------------------------------------------------------------------------
// Kernel 3: flash attention, swapped-QK^T in-register-P form.
//   sc2[kn] = mfma16x16x32(K_frag, Q_frag): lane holds P^T[k=kn*16+g*4+r][q=lr]
//   -> exactly the A-operand layout of mfma_f32_16x16x16_bf16, so PV runs as
//   4x K=16 MFMAs per d-block straight from registers: NO P LDS roundtrip.
//   Softmax: scalar running max per lane (its q=lr); defer-max THR=8 (log2);
//   row-sum via ones-MFMA. K/V double-buffered LDS, 2-phase pipeline.
// ---------------------------------------------------------------------------
__global__ __launch_bounds__(256) void attn_k(const short* __restrict__ qkv,
                                              float* __restrict__ out) {
  __shared__ __align__(16) short Ks[2][64 * 64];
  __shared__ __align__(16) short Vs[2][64 * 64];

  const int L = blockIdx.x;  // 2048 blocks
  const int xcd = L & 7, ss = L >> 3;
  const int qt = ss & 15, pg = ss >> 4;
  const int pp = xcd + (pg << 3);  // all 16 q-tiles of a head share an XCD
  const int hb = pp & 63, dir = pp >> 6;

  const short* Q = qkv + ((size_t)(dir ? 3 : 0) << 22) + ((size_t)hb << 16);
  const short* K = qkv + ((size_t)(dir ? 1 : 4) << 22) + ((size_t)hb << 16);
  const short* V = qkv + ((size_t)(dir ? 2 : 5) << 22) + ((size_t)hb << 16);
  float* O = out + ((size_t)dir << 22);

  const int t = threadIdx.x, lane = t & 63, w = t >> 6;
  const int g = lane >> 4, lr = lane & 15;

  const int qrow = (qt << 6) + (w << 4) + lr;
  bf16x8 qf[2];
  qf[0] = *(const bf16x8*)(Q + qrow * 64 + g * 8);
  qf[1] = *(const bf16x8*)(Q + qrow * 64 + 32 + g * 8);

  const bf16x4 ones4 = {0x3F80, 0x3F80, 0x3F80, 0x3F80};

  f32x4 oacc[4] = {};
  f32x4 lacc = {};
  float mrun = -3.0e38f;               // running max for q = lr (log2 units)
  const float CSC = 0.18033688f;       // (1/8) * log2(e)

  const int srow = (w << 4) + (lane >> 3);  // staging row 0..63
  const int scol = (lane & 7) << 3;

  auto stage = [&](int kt, int buf) {
#pragma unroll
    for (int i = 0; i < 2; ++i) {
      gll16(K + (size_t)((kt << 6) + srow + i * 8) * 64 + scol,
            &Ks[buf][(w << 10) + (i << 9)]);
      gll16(V + (size_t)(kt << 12) + (size_t)(srow + i * 8) * 64 + scol,
            &Vs[buf][(w << 10) + (i << 9)]);
    }
  };

  stage(0, 0);
  asm volatile("s_waitcnt vmcnt(0)" ::: "memory");
  __builtin_amdgcn_s_barrier();

  int cur = 0;
  for (int kt = 0; kt < 16; ++kt) {
    if (kt < 15) stage(kt + 1, cur ^ 1);

    // ---- S^T = K Q^T (swapped): lane gets P^T[k=kn*16+g*4+r][q=lr] ----
    f32x4 sc2[4] = {};
    __builtin_amdgcn_s_setprio(1);
#pragma unroll
    for (int dk = 0; dk < 2; ++dk) {
#pragma unroll
      for (int kn = 0; kn < 4; ++kn) {
        const int krow = kn * 16 + lr;
        const bf16x8 kf = *(const bf16x8*)
            &Ks[cur][krow * 64 +
                     ((((dk << 6) + (g << 4)) ^ ((krow & 7) << 4)) >> 1)];
        sc2[kn] = MFMA16(kf, qf[dk], sc2[kn]);
      }
    }
    __builtin_amdgcn_s_setprio(0);

    // ---- softmax (per-lane scalar state, defer-max) ----
    float tm = fmaxf(fmaxf(fmaxf(sc2[0][0], sc2[0][1]),
                           fmaxf(sc2[0][2], sc2[0][3])),
                     fmaxf(fmaxf(sc2[1][0], sc2[1][1]),
                           fmaxf(sc2[1][2], sc2[1][3])));
    tm = fmaxf(tm, fmaxf(fmaxf(fmaxf(sc2[2][0], sc2[2][1]),
                               fmaxf(sc2[2][2], sc2[2][3])),
                         fmaxf(fmaxf(sc2[3][0], sc2[3][1]),
                               fmaxf(sc2[3][2], sc2[3][3]))));
    const bool ok = __all(fmaf(tm, CSC, -mrun) <= 8.0f);
    if (!ok) {
      float t2 = fmaxf(tm, __shfl_xor(tm, 16));
      t2 = fmaxf(t2, __shfl_xor(t2, 32));
      const float mnew = fmaxf(mrun, t2 * CSC);
      const float scq = exp2f(mrun - mnew);  // scale for q = lr
      mrun = mnew;
#pragma unroll
      for (int r = 0; r < 4; ++r) {
        const float sr = __shfl(scq, (g << 2) + r);  // scale for q = g*4+r
        lacc[r] *= sr;
#pragma unroll
        for (int dn = 0; dn < 4; ++dn) oacc[dn][r] *= sr;
      }
    }

    bf16x4 pa[4];
#pragma unroll
    for (int kn = 0; kn < 4; ++kn) {
      const float p0 = exp2f(fmaf(sc2[kn][0], CSC, -mrun));
      const float p1 = exp2f(fmaf(sc2[kn][1], CSC, -mrun));
      const float p2 = exp2f(fmaf(sc2[kn][2], CSC, -mrun));
      const float p3 = exp2f(fmaf(sc2[kn][3], CSC, -mrun));
      union { unsigned u[2]; bf16x4 v; } pk;
      pk.u[0] = cvt_pk_bf16(p0, p1);
      pk.u[1] = cvt_pk_bf16(p2, p3);
      pa[kn] = pk.v;
    }

    // ---- O += P V ; l += P @ ones  (K=16 MFMAs, P straight from regs) ----
    __builtin_amdgcn_s_setprio(1);
#pragma unroll
    for (int kn = 0; kn < 4; ++kn) {
      lacc = mfma16k(pa[kn], ones4, lacc);
#pragma unroll
      for (int dn = 0; dn < 4; ++dn) {
        const int vrow = dn * 16 + lr;
        const int ch = (2 * kn + (g >> 1)) ^ (vrow & 7);  // 16B-chunk swizzle
        const bf16x4 vf = *(const bf16x4*)
            &Vs[cur][vrow * 64 + ch * 8 + ((g & 1) << 2)];
        oacc[dn] = mfma16k(pa[kn], vf, oacc[dn]);
      }
    }
    __builtin_amdgcn_s_setprio(0);

    asm volatile("s_waitcnt vmcnt(0)" ::: "memory");
    __builtin_amdgcn_s_barrier();
    cur ^= 1;
  }

  // ---- epilogue: out[b][q][h*64+d] = oacc / l ----
  const int b = hb >> 4, h = hb & 15;
  float rl[4];
#pragma unroll
  for (int r = 0; r < 4; ++r) rl[r] = 1.0f / lacc[r];
#pragma unroll
  for (int dn = 0; dn < 4; ++dn) {
#pragma unroll
    for (int r = 0; r < 4; ++r) {
      const int q = (qt << 6) + (w << 4) + (g << 2) + r;
      const int d = dn * 16 + lr;
      O[((size_t)(b * 1024 + q) << 10) + h * 64 + d] = oacc[dn][r] * rl[r];
    }
  }
}

// ---------------------------------------------------------------------------
extern "C" void kernel_launch(void* const* d_in, const int* in_sizes, int n_in,
                              void* d_out, int out_size, void* d_ws,
                              size_t ws_size, hipStream_t stream) {
  const float* x   = (const float*)d_in[0];
  const float* Wq  = (const float*)d_in[1];
  const float* bq  = (const float*)d_in[2];
  const float* Wk  = (const float*)d_in[3];
  const float* bk  = (const float*)d_in[4];
  const float* Wv  = (const float*)d_in[5];
  const float* bv  = (const float*)d_in[6];
  const float* Wq2 = (const float*)d_in[7];
  const float* bq2 = (const float*)d_in[8];
  const float* Wk2 = (const float*)d_in[9];
  const float* bk2 = (const float*)d_in[10];
  const float* Wv2 = (const float*)d_in[11];
  const float* bv2 = (const float*)d_in[12];

  char* ws = (char*)d_ws;
  short* xbf = (short*)ws;                      // 8 MB
  short* wbf = (short*)(ws + 8388608);          // 12 MB
  short* qkv = (short*)(ws + 20971520);         // 6 x 8 MB

  convert_k<<<10240, 256, 0, stream>>>(x, Wq, Wk, Wv, Wq2, Wk2, Wv2, xbf, wbf);
  proj_gemm<<<1536, 256, 0, stream>>>(xbf, wbf, bq, bk, bv, bq2, bk2,
                                      bv2, qkv);
  attn_k<<<2048, 256, 0, stream>>>(qkv, (float*)d_out);
}